// Round 15
// baseline (458.559 us; speedup 1.0000x reference)
//
#include <hip/hip_runtime.h>
#include <hip/hip_bf16.h>

#define BATCH 16
#define HH 256
#define WW 256
#define NPIX (BATCH*HH*WW)   // 1,048,576
#define NSTEPS 5
#define CBS 40               // padded codebook row stride (u16)

// frags table u16 offsets (k-order for step0, k'-order for step1)
#define W1F 0
#define W2F 9216
#define WTF 10240
#define CBF 11264
#define IDF 19456
#define W1P 20480
#define W2P 29696
#define WTP 30720
#define IDP 31744
#define CBP 32768
#define FRAGS_TOT 40960

using u16 = unsigned short;
using u32 = unsigned int;
using u8  = unsigned char;

typedef __attribute__((ext_vector_type(8))) short bf8_t;   // 8 bf16 = one MFMA A/B frag
typedef __attribute__((ext_vector_type(4))) float f4_t;    // MFMA C/D frag

#define MFMA16 __builtin_amdgcn_mfma_f32_16x16x32_bf16

// DPP min-reduce across a 16-lane row (row_ror:N = 0x120|N) — verified R4/R5
#define DPPMIN(v, CTRL) do { \
    u32 _o = (u32)__builtin_amdgcn_update_dpp((int)(v), (int)(v), (CTRL), 0xF, 0xF, false); \
    (v) = _o < (v) ? _o : (v); } while (0)

// Compiler-only reordering barrier (intra-wave LDS transpose ordering — R6/R8
// validated absmax 0.0).
#define LDS_ORDER() asm volatile("" ::: "memory")

__device__ __forceinline__ float bf2f(u32 u) {
    union { u32 i; float f; } v; v.i = u << 16; return v.f;
}
__device__ __forceinline__ u16 f2bf(float f) {
    union { float f; u32 i; } v; v.f = f;
    u32 x = v.i;
    x += 0x7fffu + ((x >> 16) & 1u);
    return (u16)(x >> 16);
}
__device__ __forceinline__ u32 pack2bf(float a, float b) {
    __hip_bfloat162 h2 = __float22bfloat162_rn(float2{a, b});
    union { __hip_bfloat162 h; u32 u; } v; v.h = h2; return v.u;
}
__device__ __forceinline__ float ldin(const void* p, int i, int f32) {
    return f32 ? ((const float*)p)[i] : bf2f(((const u16*)p)[i]);
}
__device__ __forceinline__ u16 ldbf(const void* p, int i, int f32) {
    return f32 ? f2bf(((const float*)p)[i]) : ((const u16*)p)[i];
}
__device__ __forceinline__ int sniff_f32(const void* xraw) {
    const u32* xw = (const u32*)xraw;
    int cnt = 0;
    for (int j = 0; j < 64; j++) {
        u32 w = xw[j];
        float flo = bf2f(w & 0xffffu);
        float a = fabsf(flo);
        if (flo == 0.0f || (a >= 6e-8f && a <= 64.0f)) cnt++;
    }
    return (cnt < 32) ? 1 : 0;
}
// k' channel permutation: k' = 2*(ch&15) + (ch>>4)  <=>  ch = (k'>>1)|((k'&1)<<4)
__device__ __forceinline__ int chperm(int kp) { return (kp >> 1) | ((kp & 1) << 4); }

// ============================ prep ============================
__global__ void prep_kernel(const void* x,
    const void* stem_w, const void* stem_b, const void* up1_w, const void* up1_b,
    const void* up2_w, const void* up2_b, const void* tau_w, const void* tau_b,
    const void* cb, const void* dec_w, const void* dec_b,
    u16* frags, u16* cb_bf,
    float* cn2, float* cadj, float* decdot, float* wf0,
    float* up1_bf, float* up2_bf, float* tau_bf, float* stem_bf, int* flag)
{
    int f32 = sniff_f32(x);
    int i = blockIdx.x * 256 + threadIdx.x;
    if (i == 0) *flag = f32;
    if (i < 9216) {                        // w1frag (k-order, step0)
        int slot = i >> 9, rem = i & 511, lane = rem >> 3, j = rem & 7;
        int tap = slot >> 1, nt = slot & 1;
        int co = nt*16 + (lane & 15), ci = (lane >> 4)*8 + j;
        frags[W1F + i] = ldbf(up1_w, (co*32+ci)*9 + tap, f32);
        return;
    }
    i -= 9216;
    if (i < 1024) {                        // w2frag (k-order)
        int nt = i >> 9, rem = i & 511, lane = rem >> 3, j = rem & 7;
        int co = nt*16 + (lane & 15), k = (lane >> 4)*8 + j;
        frags[W2F + i] = ldbf(up2_w, co*32 + k, f32);
        return;
    }
    i -= 1024;
    if (i < 1024) {                        // wtfrag (k-order)
        int nt = i >> 9, rem = i & 511, lane = rem >> 3, j = rem & 7;
        int co = nt*16 + (lane & 15), k = (lane >> 4)*8 + j;
        frags[WTF + i] = ldbf(tau_w, co*32 + k, f32);
        return;
    }
    i -= 1024;
    if (i < 8192) {                        // cbfrag (k-order, step0 VQ)
        int nt = i >> 9, rem = i & 511, lane = rem >> 3, j = rem & 7;
        int code = nt*16 + (lane & 15), c = (lane >> 4)*8 + j;
        frags[CBF + i] = ldbf(cb, code*32 + c, f32);
        return;
    }
    i -= 8192;
    if (i < 1024) {                        // identfrag (k-order; unused)
        int s = i >> 9, rem = i & 511, lane = rem >> 3, j = rem & 7;
        int colq = lane & 15, quad = lane >> 4;
        frags[IDF + i] = ((quad*8 + j) == (colq + s*16)) ? (u16)0x3F80 : (u16)0;
        return;
    }
    i -= 1024;
    if (i < 9216) {                        // w1p (k'-order, step1)
        int slot = i >> 9, rem = i & 511, lane = rem >> 3, j = rem & 7;
        int tap = slot >> 1, nt = slot & 1;
        int co = nt*16 + (lane & 15), ci = chperm((lane >> 4)*8 + j);
        frags[W1P + i] = ldbf(up1_w, (co*32+ci)*9 + tap, f32);
        return;
    }
    i -= 9216;
    if (i < 1024) {                        // w2p (k'-order)
        int nt = i >> 9, rem = i & 511, lane = rem >> 3, j = rem & 7;
        int co = nt*16 + (lane & 15), k = chperm((lane >> 4)*8 + j);
        frags[W2P + i] = ldbf(up2_w, co*32 + k, f32);
        return;
    }
    i -= 1024;
    if (i < 1024) {                        // wtp (k'-order)
        int nt = i >> 9, rem = i & 511, lane = rem >> 3, j = rem & 7;
        int co = nt*16 + (lane & 15), k = chperm((lane >> 4)*8 + j);
        frags[WTP + i] = ldbf(tau_w, co*32 + k, f32);
        return;
    }
    i -= 1024;
    if (i < 1024) {                        // idp (k'-order identity)
        int s = i >> 9, rem = i & 511, lane = rem >> 3, j = rem & 7;
        int colq = lane & 15, quad = lane >> 4;
        int ch = chperm(quad*8 + j);
        frags[IDP + i] = (ch == (colq + s*16)) ? (u16)0x3F80 : (u16)0;
        return;
    }
    i -= 1024;
    if (i < 8192) {                        // cbp (k'-order VQ B-frags; unused now)
        int nt = i >> 9, rem = i & 511, lane = rem >> 3, j = rem & 7;
        int code = nt*16 + (lane & 15), c = chperm((lane >> 4)*8 + j);
        frags[CBP + i] = ldbf(cb, code*32 + c, f32);
        return;
    }
    i -= 8192;
    if (i < 257*CBS) {                     // cb_bf: padded rows, k'-order channels
        int row = i / CBS, p = i - row*CBS;
        cb_bf[i] = (p < 32 && row < 256) ? ldbf(cb, row*32 + chperm(p), f32) : (u16)0;
        return;
    }
    i -= 257*CBS;
    if (i < 256) {
        float s = 0.f;
        for (int c = 0; c < 32; c++) { float v = ldin(cb, i*32+c, f32); s += v*v; }
        cn2[i] = 0.5f * s;
        return;
    }
    i -= 256;
    if (i < 256) {                         // cadj = 0.25*cn2 + 0.5
        float s = 0.f;
        for (int c = 0; c < 32; c++) { float v = ldin(cb, i*32+c, f32); s += v*v; }
        cadj[i] = 0.25f * (0.5f * s) + 0.5f;
        return;
    }
    i -= 256;
    if (i < 256) {
        float s = ldin(dec_b, 0, f32);
        for (int c = 0; c < 32; c++) s += ldin(dec_w, c, f32) * ldin(cb, i*32+c, f32);
        decdot[i] = s;
        return;
    }
    i -= 256;
    if (i < 288) {
        int tap = i >> 5, co = i & 31;
        wf0[i] = ldin(stem_w, co*9 + tap, f32);
        return;
    }
    i -= 288;
    if (i < 32) { up1_bf[i]  = ldin(up1_b, i, f32); return; }
    i -= 32;
    if (i < 32) { up2_bf[i]  = ldin(up2_b, i, f32); return; }
    i -= 32;
    if (i < 32) { tau_bf[i]  = ldin(tau_b, i, f32); return; }
    i -= 32;
    if (i < 32) { stem_bf[i] = ldin(stem_b, i, f32); return; }
}

// ===================== step 1 (stem fused) — R10 body verbatim (proven 0.0) ==========
__global__ __launch_bounds__(256) void step0_kernel(
    const void* __restrict__ xraw, const int* __restrict__ flagp,
    u8* __restrict__ idx_out,
    const u16* __restrict__ fragsg, const float* __restrict__ cn2,
    const float* __restrict__ up1_b, const float* __restrict__ up2_b,
    const float* __restrict__ tau_b, const float* __restrict__ wf0,
    const float* __restrict__ stem_bf)
{
    __shared__ __align__(16) u16 smem[31872];   // 63744 B
    u16* w1f   = smem;            // 9216
    u16* w2f   = smem + 9216;     // 1024
    u16* wtf   = smem + 10240;    // 1024
    u16* cbf   = smem + 11264;    // 8192
    u16* tileq = smem + 19456;    // 10368 [quad][py*18+px][8]
    u16* hzb   = smem + 29824;    // 2048
    float* xs  = (float*)hzb;     // alias (pre-compute phase only)

    int tid = threadIdx.x;
    int lane = tid & 63, wave = tid >> 6;
    int col = lane & 15, quad = lane >> 4;
    int b = blockIdx.z, x0 = blockIdx.x * 16, y0 = blockIdx.y * 16;

    {
        const uint4* s4 = (const uint4*)fragsg;
        uint4* d4 = (uint4*)smem;
        for (int i = tid; i < 2432; i += 256) d4[i] = s4[i];   // k-order tables
    }

    {
        int f32 = *flagp;
        for (int pp = tid; pp < 400; pp += 256) {
            int r = pp / 20, c = pp - r*20;
            int gy = y0 - 2 + r, gx = x0 - 2 + c;
            float v = 0.f;
            if ((unsigned)gy < 256u && (unsigned)gx < 256u)
                v = ldin(xraw, (b << 16) | (gy << 8) | gx, f32);
            xs[pp] = v;
        }
        __syncthreads();
        for (int pp = tid; pp < 324; pp += 256) {
            int r = pp / 18, c = pp - r*18;
            int gy = y0 - 1 + r, gx = x0 - 1 + c;
            uint4 qv[4] = {{0,0,0,0},{0,0,0,0},{0,0,0,0},{0,0,0,0}};
            if ((unsigned)gy < 256u && (unsigned)gx < 256u) {
                float acc[32];
#pragma unroll
                for (int co = 0; co < 32; co++) acc[co] = stem_bf[co];
#pragma unroll
                for (int tap = 0; tap < 9; tap++) {
                    float v = xs[(r + tap/3)*20 + (c + tap%3)];
                    const float* w = &wf0[tap*32];
#pragma unroll
                    for (int co = 0; co < 32; co++) acc[co] = fmaf(v, w[co], acc[co]);
                }
                u32* ow = (u32*)qv;
#pragma unroll
                for (int j = 0; j < 16; j++)
                    ow[j] = pack2bf(fmaxf(acc[2*j], 0.f), fmaxf(acc[2*j+1], 0.f));
            }
#pragma unroll
            for (int q = 0; q < 4; q++)
                *(uint4*)&tileq[(q*324 + pp)*8] = qv[q];
        }
        __syncthreads();
    }
    __syncthreads();

    float cn2adj[16];
#pragma unroll
    for (int nt = 0; nt < 16; nt++) cn2adj[nt] = 0.25f*cn2[nt*16+col] + 0.5f;
    float bu1C0 = up1_b[col], bu1C1 = up1_b[col+16];
    float bu2_0 = up2_b[col], bu2_1 = up2_b[col+16];
    float bt0 = tau_b[col],   bt1 = tau_b[col+16];
    int qk0 = col >> 3, e = col & 7;
    u16* hzw = &hzb[wave*512];
    int wy = wave * 4;
    f4_t kz = {0.f,0.f,0.f,0.f};

    bf8_t rows[4][3];
#pragma unroll
    for (int i = 0; i < 4; i++)
#pragma unroll
        for (int dx = 0; dx < 3; dx++)
            rows[i][dx] = *(const bf8_t*)&tileq[(quad*324 + (wy+i)*18 + col+dx)*8];

#pragma unroll
    for (int rrp = 0; rrp < 2; rrp++) {
        if (rrp) {
#pragma unroll
            for (int dx = 0; dx < 3; dx++) {
                rows[0][dx] = rows[2][dx];
                rows[1][dx] = rows[3][dx];
                rows[2][dx] = *(const bf8_t*)&tileq[(quad*324 + (wy+4)*18 + col+dx)*8];
                rows[3][dx] = *(const bf8_t*)&tileq[(quad*324 + (wy+5)*18 + col+dx)*8];
            }
        }
        f4_t aA0 = kz, aA1 = kz, aB0 = kz, aB1 = kz;
#pragma unroll
        for (int t = 0; t < 9; t++) {
            int dy = t/3, dx = t - dy*3;
            bf8_t wA = *(const bf8_t*)&w1f[((t*2+0)*64 + lane)*8];
            bf8_t wB = *(const bf8_t*)&w1f[((t*2+1)*64 + lane)*8];
            aA0 = MFMA16(rows[dy  ][dx], wA, aA0, 0, 0, 0);
            aA1 = MFMA16(rows[dy  ][dx], wB, aA1, 0, 0, 0);
            aB0 = MFMA16(rows[dy+1][dx], wA, aB0, 0, 0, 0);
            aB1 = MFMA16(rows[dy+1][dx], wB, aB1, 0, 0, 0);
        }
#pragma unroll
        for (int r = 0; r < 4; r++) {
            int px = quad*4 + r;
            u32 pk = pack2bf(fmaxf(aA0[r] + bu1C0, 0.f), fmaxf(aA1[r] + bu1C1, 0.f));
            hzw[((qk0  )*16 + px)*8 + e] = (u16)pk;
            hzw[((qk0+2)*16 + px)*8 + e] = (u16)(pk >> 16);
        }
        asm volatile("s_waitcnt lgkmcnt(0)" ::: "memory");
        bf8_t hA0 = *(const bf8_t*)&hzw[(quad*16 + col)*8];
#pragma unroll
        for (int r = 0; r < 4; r++) {
            int px = quad*4 + r;
            u32 pk = pack2bf(fmaxf(aB0[r] + bu1C0, 0.f), fmaxf(aB1[r] + bu1C1, 0.f));
            hzw[((qk0  )*16 + px)*8 + e] = (u16)pk;
            hzw[((qk0+2)*16 + px)*8 + e] = (u16)(pk >> 16);
        }
        asm volatile("s_waitcnt lgkmcnt(0)" ::: "memory");
        bf8_t hA1 = *(const bf8_t*)&hzw[(quad*16 + col)*8];

        bf8_t w20 = *(const bf8_t*)&w2f[(0*64+lane)*8];
        bf8_t w21 = *(const bf8_t*)&w2f[(1*64+lane)*8];
        bf8_t wt0 = *(const bf8_t*)&wtf[(0*64+lane)*8];
        bf8_t wt1 = *(const bf8_t*)&wtf[(1*64+lane)*8];
        bf8_t sA0 = rows[1][1], sA1 = rows[2][1];
        f4_t d00 = MFMA16(hA0, w20, kz, 0, 0, 0);
        f4_t d01 = MFMA16(hA0, w21, kz, 0, 0, 0);
        f4_t d10 = MFMA16(hA1, w20, kz, 0, 0, 0);
        f4_t d11 = MFMA16(hA1, w21, kz, 0, 0, 0);
        f4_t t00 = MFMA16(sA0, wt0, kz, 0, 0, 0);
        f4_t t01 = MFMA16(sA0, wt1, kz, 0, 0, 0);
        f4_t t10 = MFMA16(sA1, wt0, kz, 0, 0, 0);
        f4_t t11 = MFMA16(sA1, wt1, kz, 0, 0, 0);

        int py0 = wy + rrp*2 + 1, py1 = py0 + 1;
#pragma unroll
        for (int r = 0; r < 4; r++) {
            int px = quad*4 + r, pxt = 1 + px;
            float s0 = bf2f(tileq[((col>>3    )*324 + py0*18 + pxt)*8 + (col&7)]);
            float s1 = bf2f(tileq[(((col>>3)+2)*324 + py0*18 + pxt)*8 + (col&7)]);
            float dl0 = d00[r] + bu2_0, tv0 = t00[r] + bt0;
            float be0 = 1.0f / (1.0f + __expf(-tv0));
            float dl1 = d01[r] + bu2_1, tv1 = t01[r] + bt1;
            float be1 = 1.0f / (1.0f + __expf(-tv1));
            u32 pk = pack2bf(-0.25f * (dl0 + be0*(s0 - dl0)),
                             -0.25f * (dl1 + be1*(s1 - dl1)));
            hzw[((qk0  )*16 + px)*8 + e] = (u16)pk;
            hzw[((qk0+2)*16 + px)*8 + e] = (u16)(pk >> 16);
        }
        asm volatile("s_waitcnt lgkmcnt(0)" ::: "memory");
        bf8_t zA0 = *(const bf8_t*)&hzw[(quad*16 + col)*8];
#pragma unroll
        for (int r = 0; r < 4; r++) {
            int px = quad*4 + r, pxt = 1 + px;
            float s0 = bf2f(tileq[((col>>3    )*324 + py1*18 + pxt)*8 + (col&7)]);
            float s1 = bf2f(tileq[(((col>>3)+2)*324 + py1*18 + pxt)*8 + (col&7)]);
            float dl0 = d10[r] + bu2_0, tv0 = t10[r] + bt0;
            float be0 = 1.0f / (1.0f + __expf(-tv0));
            float dl1 = d11[r] + bu2_1, tv1 = t11[r] + bt1;
            float be1 = 1.0f / (1.0f + __expf(-tv1));
            u32 pk = pack2bf(-0.25f * (dl0 + be0*(s0 - dl0)),
                             -0.25f * (dl1 + be1*(s1 - dl1)));
            hzw[((qk0  )*16 + px)*8 + e] = (u16)pk;
            hzw[((qk0+2)*16 + px)*8 + e] = (u16)(pk >> 16);
        }
        asm volatile("s_waitcnt lgkmcnt(0)" ::: "memory");
        bf8_t zA1 = *(const bf8_t*)&hzw[(quad*16 + col)*8];

        u32 b0[4], b1[4];
#pragma unroll
        for (int r = 0; r < 4; r++) { b0[r] = 0xFFFFFFFFu; b1[r] = 0xFFFFFFFFu; }
#pragma unroll
        for (int nt = 0; nt < 16; nt++) {
            bf8_t cf = *(const bf8_t*)&cbf[(nt*64 + lane)*8];
            f4_t ci = {cn2adj[nt], cn2adj[nt], cn2adj[nt], cn2adj[nt]};
            f4_t s0 = MFMA16(zA0, cf, ci, 0, 0, 0);
            f4_t s1 = MFMA16(zA1, cf, ci, 0, 0, 0);
            u32 code = (u32)(nt*16) | (u32)col;
#pragma unroll
            for (int r = 0; r < 4; r++) {
                u32 k0 = (__builtin_bit_cast(u32, s0[r]) & 0xFFFFFF00u) | code;
                u32 k1 = (__builtin_bit_cast(u32, s1[r]) & 0xFFFFFF00u) | code;
                b0[r] = k0 < b0[r] ? k0 : b0[r];
                b1[r] = k1 < b1[r] ? k1 : b1[r];
            }
        }
#pragma unroll
        for (int r = 0; r < 4; r++) {
            DPPMIN(b0[r], 0x121); DPPMIN(b0[r], 0x122);
            DPPMIN(b0[r], 0x124); DPPMIN(b0[r], 0x128);
            DPPMIN(b1[r], 0x121); DPPMIN(b1[r], 0x122);
            DPPMIN(b1[r], 0x124); DPPMIN(b1[r], 0x128);
        }
        int yr = y0 + wy + rrp*2;
        if (col < 4) {
            idx_out[(b*256 + yr    )*256 + x0 + quad*4 + col] = (u8)(b0[col] & 255u);
            idx_out[(b*256 + yr + 1)*256 + x0 + quad*4 + col] = (u8)(b1[col] & 255u);
        }
    }
}

// ===================== steps 2..5: row-quad groups (shared B-frag reads x4) ==========
// R14's 16x32 tile + th loop. NEW: each wave's 4 rows processed as ONE group —
// conv t-loop does 8 MFMAs per (2 w1 reads + 4 gathers); VQ loop's 16 cf reads
// feed 4 zA each. Per-row accumulate order unchanged -> bit-identical to R14.
__global__ __launch_bounds__(256) void step1_kernel(
    const u8* __restrict__ idx_in, u8* __restrict__ idx_out,
    const u16* __restrict__ fragsg, const u16* __restrict__ cbr_g,
    const float* __restrict__ cadj_g,
    const float* __restrict__ up1_b, const float* __restrict__ up2_b,
    const float* __restrict__ tau_b)
{
    __shared__ __align__(16) u16 smem[24104];   // 48208 B
    u16* w1f = smem;                       // 9216 (k'-order)
    u16* w2f = smem + 9216;                // 1024
    u16* wtf = smem + 10240;               // 1024
    u16* cbr = smem + 11264;               // 10280 (257 x CBS, k'-order)
    float* cadjf = (float*)(smem + 21544); // 256 f32
    u16* hzb = smem + 22056;               // 2048

    int tid = threadIdx.x;
    int lane = tid & 63, wave = tid >> 6;
    int col = lane & 15, quad = lane >> 4;
    int b = blockIdx.z, x0 = blockIdx.x * 16, y0 = blockIdx.y * 32;
    int wy = wave * 4;

    // identity B-frags (k'-order, global/L1 once; 8 regs)
    bf8_t id0 = *(const bf8_t*)&fragsg[IDP + (0*64+lane)*8];
    bf8_t id1 = *(const bf8_t*)&fragsg[IDP + (1*64+lane)*8];

    // tables -> LDS: w1p|w2p|wtp = 22528 B = 1408 uint4, cbr = 1285, cadj = 64
    {
        const uint4* s4 = (const uint4*)(fragsg + W1P);
        uint4* d4 = (uint4*)smem;
        for (int i = tid; i < 1408; i += 256) d4[i] = s4[i];
        const uint4* c4 = (const uint4*)cbr_g;
        uint4* e4 = (uint4*)cbr;
        for (int i = tid; i < 1285; i += 256) e4[i] = c4[i];
        const uint4* a4 = (const uint4*)cadj_g;
        uint4* f4p = (uint4*)cadjf;
        if (tid < 64) f4p[tid] = a4[tid];
    }
    __syncthreads();

    float bu1C0 = up1_b[col], bu1C1 = up1_b[col+16];
    float bu2_0 = up2_b[col], bu2_1 = up2_b[col+16];
    float bt0 = tau_b[col],   bt1 = tau_b[col+16];
    u16* hzw = &hzb[wave*512];
    u32* hz32 = (u32*)hzw;
    f4_t kz = {0.f,0.f,0.f,0.f};

    for (int th = 0; th < 2; th++) {
        int yb = y0 + th*16;

        // packed neighborhood codes for this half: kp[tr] = c0|c1<<9|c2<<18
        u32 kp[6];
#pragma unroll
        for (int tr = 0; tr < 6; tr++) {
            u32 pk = 0;
#pragma unroll
            for (int dx = 0; dx < 3; dx++) {
                int gy = yb - 1 + wy + tr, gx = x0 - 1 + col + dx;
                bool ok = ((unsigned)gy < 256u) & ((unsigned)gx < 256u);
                u32 c = ok ? (u32)idx_in[(b << 16) | (gy << 8) | gx] : 256u;
                pk |= c << (9*dx);
            }
            kp[tr] = pk;
        }

        // ---- row-quad conv3x3: acc[r4][0..1], one t-loop for all 4 rows ----
        f4_t acc[4][2];
#pragma unroll
        for (int r4 = 0; r4 < 4; r4++) { acc[r4][0] = kz; acc[r4][1] = kz; }
        bf8_t sA[4];
#pragma unroll
        for (int t = 0; t < 9; t++) {
            int dy = t/3, dx = t - dy*3;
            bf8_t wA = *(const bf8_t*)&w1f[((t*2+0)*64 + lane)*8];
            bf8_t wB = *(const bf8_t*)&w1f[((t*2+1)*64 + lane)*8];
#pragma unroll
            for (int r4 = 0; r4 < 4; r4++) {
                int k = (int)((kp[r4+dy] >> (9*dx)) & 511u);
                bf8_t f = *(const bf8_t*)&cbr[k*CBS + quad*8];
                if (t == 4) sA[r4] = f;
                acc[r4][0] = MFMA16(f, wA, acc[r4][0], 0, 0, 0);
                acc[r4][1] = MFMA16(f, wB, acc[r4][1], 0, 0, 0);
            }
        }

        bf8_t w20 = *(const bf8_t*)&w2f[(0*64+lane)*8];
        bf8_t w21 = *(const bf8_t*)&w2f[(1*64+lane)*8];
        bf8_t wt0 = *(const bf8_t*)&wtf[(0*64+lane)*8];
        bf8_t wt1 = *(const bf8_t*)&wtf[(1*64+lane)*8];

        // ---- tail: serialized per row (caps live AGPRs); zA accumulates ----
        bf8_t zA[4];
#pragma unroll
        for (int r4 = 0; r4 < 4; r4++) {
            // h transpose (u32 m-major writes, b128 read)
#pragma unroll
            for (int r = 0; r < 4; r++) {
                int px = quad*4 + r;
                hz32[px*16 + col] = pack2bf(fmaxf(acc[r4][0][r] + bu1C0, 0.f),
                                            fmaxf(acc[r4][1][r] + bu1C1, 0.f));
            }
            LDS_ORDER();
            bf8_t hA = *(const bf8_t*)&hzw[col*32 + quad*8];
            LDS_ORDER();
            f4_t d0 = MFMA16(hA, w20, kz, 0, 0, 0);
            f4_t d1 = MFMA16(hA, w21, kz, 0, 0, 0);
            f4_t t0 = MFMA16(sA[r4], wt0, kz, 0, 0, 0);
            f4_t t1 = MFMA16(sA[r4], wt1, kz, 0, 0, 0);
            f4_t Sl = MFMA16(sA[r4], id0, kz, 0, 0, 0);
            f4_t Sh = MFMA16(sA[r4], id1, kz, 0, 0, 0);
#pragma unroll
            for (int r = 0; r < 4; r++) {
                int px = quad*4 + r;
                float dl0 = d0[r] + bu2_0, tv0 = t0[r] + bt0;
                float be0 = 1.0f / (1.0f + __expf(-tv0));
                float dl1 = d1[r] + bu2_1, tv1 = t1[r] + bt1;
                float be1 = 1.0f / (1.0f + __expf(-tv1));
                hz32[px*16 + col] = pack2bf(-0.25f * (dl0 + be0*(Sl[r] - dl0)),
                                            -0.25f * (dl1 + be1*(Sh[r] - dl1)));
            }
            LDS_ORDER();
            zA[r4] = *(const bf8_t*)&hzw[col*32 + quad*8];
            LDS_ORDER();
        }

        // ---- VQ: 16 cf reads, each feeds 4 rows' MFMAs ----
        u32 bk[4][4];
#pragma unroll
        for (int r4 = 0; r4 < 4; r4++)
#pragma unroll
            for (int r = 0; r < 4; r++) bk[r4][r] = 0xFFFFFFFFu;
#pragma unroll
        for (int nt = 0; nt < 16; nt++) {
            bf8_t cf = *(const bf8_t*)&cbr[(nt*16 + col)*CBS + quad*8];
            float ca = cadjf[nt*16 + col];
            f4_t ci = {ca, ca, ca, ca};
            u32 code = (u32)(nt*16) | (u32)col;
#pragma unroll
            for (int r4 = 0; r4 < 4; r4++) {
                f4_t sc = MFMA16(zA[r4], cf, ci, 0, 0, 0);
#pragma unroll
                for (int r = 0; r < 4; r++) {
                    u32 k0 = (__builtin_bit_cast(u32, sc[r]) & 0xFFFFFF00u) | code;
                    bk[r4][r] = k0 < bk[r4][r] ? k0 : bk[r4][r];
                }
            }
        }
#pragma unroll
        for (int r4 = 0; r4 < 4; r4++) {
#pragma unroll
            for (int r = 0; r < 4; r++) {
                DPPMIN(bk[r4][r], 0x121); DPPMIN(bk[r4][r], 0x122);
                DPPMIN(bk[r4][r], 0x124); DPPMIN(bk[r4][r], 0x128);
            }
            int yr = yb + wy + r4;
            if (col < 4)
                idx_out[(b*256 + yr)*256 + x0 + quad*4 + col] = (u8)(bk[r4][col] & 255u);
        }
    }
}

// ============================ dec ============================
__global__ __launch_bounds__(256) void dec_kernel(const u8* __restrict__ idx,
        const float* __restrict__ decdot, const int* __restrict__ flagp,
        void* __restrict__ out)
{
    int p = blockIdx.x * 256 + threadIdx.x;
    float s = decdot[idx[p]];
    float r = 1.0f / (1.0f + __expf(-s));
    if (*flagp) ((float*)out)[p] = r;
    else        ((u16*)out)[p]   = f2bf(r);
}

extern "C" void kernel_launch(void* const* d_in, const int* in_sizes, int n_in,
                              void* d_out, int out_size, void* d_ws, size_t ws_size,
                              hipStream_t stream)
{
    const void* x      = d_in[0];
    const void* stem_w = d_in[1];
    const void* stem_b = d_in[2];
    const void* up1_w  = d_in[3];
    const void* up1_b  = d_in[4];
    const void* up2_w  = d_in[5];
    const void* up2_b  = d_in[6];
    const void* tau_w  = d_in[7];
    const void* tau_b  = d_in[8];
    const void* cb     = d_in[9];
    const void* dec_w  = d_in[10];
    const void* dec_b  = d_in[11];
    // d_in[12] = n_steps (fixed at 5 by the problem definition)

    char* ws = (char*)d_ws;
    size_t off = 0;
    auto carve = [&](size_t bytes) -> void* {
        void* p = ws + off;
        off += (bytes + 255) & ~(size_t)255;
        return p;
    };
    u8*    idxA    = (u8*)   carve(NPIX);
    u8*    idxB    = (u8*)   carve(NPIX);
    u16*   frags   = (u16*)  carve(FRAGS_TOT * 2);  // k-order + k'-order tables
    u16*   cb_bf   = (u16*)  carve(257*CBS * 2);    // k'-order padded rows
    float* cn2     = (float*)carve(256 * 4);
    float* cadj    = (float*)carve(256 * 4);
    float* decdot  = (float*)carve(256 * 4);
    float* wf0     = (float*)carve(288 * 4);
    float* up1_bf  = (float*)carve(32 * 4);
    float* up2_bf  = (float*)carve(32 * 4);
    float* tau_bf  = (float*)carve(32 * 4);
    float* stem_bf = (float*)carve(32 * 4);
    int*   flag    = (int*)  carve(4);

    prep_kernel<<<205, 256, 0, stream>>>(x, stem_w, stem_b, up1_w, up1_b,
        up2_w, up2_b, tau_w, tau_b, cb, dec_w, dec_b,
        frags, cb_bf, cn2, cadj, decdot, wf0,
        up1_bf, up2_bf, tau_bf, stem_bf, flag);

    dim3 g0(WW/16, HH/16, BATCH);
    step0_kernel<<<g0, 256, 0, stream>>>(x, flag, idxA,
        frags, cn2, up1_bf, up2_bf, tau_bf, wf0, stem_bf);
    dim3 g1(WW/16, HH/32, BATCH);
    u8* cur = idxA; u8* nxt = idxB;
    for (int t = 1; t < NSTEPS; t++) {
        step1_kernel<<<g1, 256, 0, stream>>>(cur, nxt, frags, cb_bf, cadj,
                                             up1_bf, up2_bf, tau_bf);
        u8* tmp = cur; cur = nxt; nxt = tmp;
    }
    dec_kernel<<<NPIX/256, 256, 0, stream>>>(cur, decdot, flag, d_out);
}

// Round 16
// 454.727 us; speedup vs baseline: 1.0084x; 1.0084x over previous
//
#include <hip/hip_runtime.h>
#include <hip/hip_bf16.h>

#define BATCH 16
#define HH 256
#define WW 256
#define NPIX (BATCH*HH*WW)   // 1,048,576
#define NSTEPS 5
#define CBS 40               // padded codebook row stride (u16)

// frags table u16 offsets (k-order for legacy, k'-order for step0/step1)
#define W1F 0
#define W2F 9216
#define WTF 10240
#define CBF 11264
#define IDF 19456
#define W1P 20480
#define W2P 29696
#define WTP 30720
#define IDP 31744
#define CBP 32768
#define FRAGS_TOT 40960

using u16 = unsigned short;
using u32 = unsigned int;
using u8  = unsigned char;

typedef __attribute__((ext_vector_type(8))) short bf8_t;   // 8 bf16 = one MFMA A/B frag
typedef __attribute__((ext_vector_type(4))) float f4_t;    // MFMA C/D frag

#define MFMA16 __builtin_amdgcn_mfma_f32_16x16x32_bf16

// DPP min-reduce across a 16-lane row (row_ror:N = 0x120|N) — verified R4/R5
#define DPPMIN(v, CTRL) do { \
    u32 _o = (u32)__builtin_amdgcn_update_dpp((int)(v), (int)(v), (CTRL), 0xF, 0xF, false); \
    (v) = _o < (v) ? _o : (v); } while (0)

// Compiler-only reordering barrier (intra-wave LDS transpose ordering — R6/R8
// validated absmax 0.0).
#define LDS_ORDER() asm volatile("" ::: "memory")

__device__ __forceinline__ float bf2f(u32 u) {
    union { u32 i; float f; } v; v.i = u << 16; return v.f;
}
__device__ __forceinline__ u16 f2bf(float f) {
    union { float f; u32 i; } v; v.f = f;
    u32 x = v.i;
    x += 0x7fffu + ((x >> 16) & 1u);
    return (u16)(x >> 16);
}
__device__ __forceinline__ u32 pack2bf(float a, float b) {
    __hip_bfloat162 h2 = __float22bfloat162_rn(float2{a, b});
    union { __hip_bfloat162 h; u32 u; } v; v.h = h2; return v.u;
}
__device__ __forceinline__ float ldin(const void* p, int i, int f32) {
    return f32 ? ((const float*)p)[i] : bf2f(((const u16*)p)[i]);
}
__device__ __forceinline__ u16 ldbf(const void* p, int i, int f32) {
    return f32 ? f2bf(((const float*)p)[i]) : ((const u16*)p)[i];
}
__device__ __forceinline__ int sniff_f32(const void* xraw) {
    const u32* xw = (const u32*)xraw;
    int cnt = 0;
    for (int j = 0; j < 64; j++) {
        u32 w = xw[j];
        float flo = bf2f(w & 0xffffu);
        float a = fabsf(flo);
        if (flo == 0.0f || (a >= 6e-8f && a <= 64.0f)) cnt++;
    }
    return (cnt < 32) ? 1 : 0;
}
// k' channel permutation: k' = 2*(ch&15) + (ch>>4)  <=>  ch = (k'>>1)|((k'&1)<<4)
__device__ __forceinline__ int chperm(int kp) { return (kp >> 1) | ((kp & 1) << 4); }

// ============================ prep ============================
__global__ void prep_kernel(const void* x,
    const void* stem_w, const void* stem_b, const void* up1_w, const void* up1_b,
    const void* up2_w, const void* up2_b, const void* tau_w, const void* tau_b,
    const void* cb, const void* dec_w, const void* dec_b,
    u16* frags, u16* cb_bf,
    float* cn2, float* cadj, float* decdot, float* wf0,
    float* up1_bf, float* up2_bf, float* tau_bf, float* stem_bf, int* flag)
{
    int f32 = sniff_f32(x);
    int i = blockIdx.x * 256 + threadIdx.x;
    if (i == 0) *flag = f32;
    if (i < 9216) {                        // w1frag (k-order; legacy, unused)
        int slot = i >> 9, rem = i & 511, lane = rem >> 3, j = rem & 7;
        int tap = slot >> 1, nt = slot & 1;
        int co = nt*16 + (lane & 15), ci = (lane >> 4)*8 + j;
        frags[W1F + i] = ldbf(up1_w, (co*32+ci)*9 + tap, f32);
        return;
    }
    i -= 9216;
    if (i < 1024) {                        // w2frag (k-order; legacy)
        int nt = i >> 9, rem = i & 511, lane = rem >> 3, j = rem & 7;
        int co = nt*16 + (lane & 15), k = (lane >> 4)*8 + j;
        frags[W2F + i] = ldbf(up2_w, co*32 + k, f32);
        return;
    }
    i -= 1024;
    if (i < 1024) {                        // wtfrag (k-order; legacy)
        int nt = i >> 9, rem = i & 511, lane = rem >> 3, j = rem & 7;
        int co = nt*16 + (lane & 15), k = (lane >> 4)*8 + j;
        frags[WTF + i] = ldbf(tau_w, co*32 + k, f32);
        return;
    }
    i -= 1024;
    if (i < 8192) {                        // cbfrag (k-order; legacy)
        int nt = i >> 9, rem = i & 511, lane = rem >> 3, j = rem & 7;
        int code = nt*16 + (lane & 15), c = (lane >> 4)*8 + j;
        frags[CBF + i] = ldbf(cb, code*32 + c, f32);
        return;
    }
    i -= 8192;
    if (i < 1024) {                        // identfrag (k-order; legacy)
        int s = i >> 9, rem = i & 511, lane = rem >> 3, j = rem & 7;
        int colq = lane & 15, quad = lane >> 4;
        frags[IDF + i] = ((quad*8 + j) == (colq + s*16)) ? (u16)0x3F80 : (u16)0;
        return;
    }
    i -= 1024;
    if (i < 9216) {                        // w1p (k'-order)
        int slot = i >> 9, rem = i & 511, lane = rem >> 3, j = rem & 7;
        int tap = slot >> 1, nt = slot & 1;
        int co = nt*16 + (lane & 15), ci = chperm((lane >> 4)*8 + j);
        frags[W1P + i] = ldbf(up1_w, (co*32+ci)*9 + tap, f32);
        return;
    }
    i -= 9216;
    if (i < 1024) {                        // w2p (k'-order)
        int nt = i >> 9, rem = i & 511, lane = rem >> 3, j = rem & 7;
        int co = nt*16 + (lane & 15), k = chperm((lane >> 4)*8 + j);
        frags[W2P + i] = ldbf(up2_w, co*32 + k, f32);
        return;
    }
    i -= 1024;
    if (i < 1024) {                        // wtp (k'-order)
        int nt = i >> 9, rem = i & 511, lane = rem >> 3, j = rem & 7;
        int co = nt*16 + (lane & 15), k = chperm((lane >> 4)*8 + j);
        frags[WTP + i] = ldbf(tau_w, co*32 + k, f32);
        return;
    }
    i -= 1024;
    if (i < 1024) {                        // idp (k'-order identity)
        int s = i >> 9, rem = i & 511, lane = rem >> 3, j = rem & 7;
        int colq = lane & 15, quad = lane >> 4;
        int ch = chperm(quad*8 + j);
        frags[IDP + i] = (ch == (colq + s*16)) ? (u16)0x3F80 : (u16)0;
        return;
    }
    i -= 1024;
    if (i < 8192) {                        // cbp (k'-order VQ B-frags)
        int nt = i >> 9, rem = i & 511, lane = rem >> 3, j = rem & 7;
        int code = nt*16 + (lane & 15), c = chperm((lane >> 4)*8 + j);
        frags[CBP + i] = ldbf(cb, code*32 + c, f32);
        return;
    }
    i -= 8192;
    if (i < 257*CBS) {                     // cb_bf: padded rows, k'-order channels
        int row = i / CBS, p = i - row*CBS;
        cb_bf[i] = (p < 32 && row < 256) ? ldbf(cb, row*32 + chperm(p), f32) : (u16)0;
        return;
    }
    i -= 257*CBS;
    if (i < 256) {
        float s = 0.f;
        for (int c = 0; c < 32; c++) { float v = ldin(cb, i*32+c, f32); s += v*v; }
        cn2[i] = 0.5f * s;
        return;
    }
    i -= 256;
    if (i < 256) {                         // cadj = 0.25*cn2 + 0.5
        float s = 0.f;
        for (int c = 0; c < 32; c++) { float v = ldin(cb, i*32+c, f32); s += v*v; }
        cadj[i] = 0.25f * (0.5f * s) + 0.5f;
        return;
    }
    i -= 256;
    if (i < 256) {
        float s = ldin(dec_b, 0, f32);
        for (int c = 0; c < 32; c++) s += ldin(dec_w, c, f32) * ldin(cb, i*32+c, f32);
        decdot[i] = s;
        return;
    }
    i -= 256;
    if (i < 288) {
        int tap = i >> 5, co = i & 31;
        wf0[i] = ldin(stem_w, co*9 + tap, f32);
        return;
    }
    i -= 288;
    if (i < 32) { up1_bf[i]  = ldin(up1_b, i, f32); return; }
    i -= 32;
    if (i < 32) { up2_bf[i]  = ldin(up2_b, i, f32); return; }
    i -= 32;
    if (i < 32) { tau_bf[i]  = ldin(tau_b, i, f32); return; }
    i -= 32;
    if (i < 32) { stem_bf[i] = ldin(stem_b, i, f32); return; }
}

// ===================== step 1 (stem fused) — R16: k' tables + u32 transposes ==========
// Ported from step1's verified pieces: tile in k' channel order, u32 m-major
// transposes (4-way vs 8-way banked u16), identity-MFMA s_el (kills 32
// scattered ds_read_u16/rrp), VQ B-frags from cbp (k', lane-contiguous).
__global__ __launch_bounds__(256) void step0_kernel(
    const void* __restrict__ xraw, const int* __restrict__ flagp,
    u8* __restrict__ idx_out,
    const u16* __restrict__ fragsg, const float* __restrict__ cn2,
    const float* __restrict__ up1_b, const float* __restrict__ up2_b,
    const float* __restrict__ tau_b, const float* __restrict__ wf0,
    const float* __restrict__ stem_bf)
{
    __shared__ __align__(16) u16 smem[31872];   // 63744 B
    u16* w1f   = smem;            // 9216 (k')
    u16* w2f   = smem + 9216;     // 1024 (k')
    u16* wtf   = smem + 10240;    // 1024 (k')
    u16* cbf   = smem + 11264;    // 8192 (k' cbp)
    u16* tileq = smem + 19456;    // 10368 [quad][py*18+px][8] (k' channel order)
    u16* hzb   = smem + 29824;    // 2048
    float* xs  = (float*)hzb;     // alias (pre-compute phase only)

    int tid = threadIdx.x;
    int lane = tid & 63, wave = tid >> 6;
    int col = lane & 15, quad = lane >> 4;
    int b = blockIdx.z, x0 = blockIdx.x * 16, y0 = blockIdx.y * 16;

    // identity B-frags (k'-order, global/L1)
    bf8_t id0 = *(const bf8_t*)&fragsg[IDP + (0*64+lane)*8];
    bf8_t id1 = *(const bf8_t*)&fragsg[IDP + (1*64+lane)*8];

    // copy k' tables: w1p|w2p|wtp = 11264 u16 = 1408 uint4; cbp = 8192 u16 = 1024 uint4
    {
        const uint4* s4 = (const uint4*)(fragsg + W1P);
        uint4* d4 = (uint4*)smem;
        for (int i = tid; i < 1408; i += 256) d4[i] = s4[i];
        const uint4* c4 = (const uint4*)(fragsg + CBP);
        uint4* e4 = (uint4*)cbf;
        for (int i = tid; i < 1024; i += 256) e4[i] = c4[i];
    }

    {
        int f32 = *flagp;
        for (int pp = tid; pp < 400; pp += 256) {
            int r = pp / 20, c = pp - r*20;
            int gy = y0 - 2 + r, gx = x0 - 2 + c;
            float v = 0.f;
            if ((unsigned)gy < 256u && (unsigned)gx < 256u)
                v = ldin(xraw, (b << 16) | (gy << 8) | gx, f32);
            xs[pp] = v;
        }
        __syncthreads();
        for (int pp = tid; pp < 324; pp += 256) {
            int r = pp / 18, c = pp - r*18;
            int gy = y0 - 1 + r, gx = x0 - 1 + c;
            uint4 qv[4] = {{0,0,0,0},{0,0,0,0},{0,0,0,0},{0,0,0,0}};
            if ((unsigned)gy < 256u && (unsigned)gx < 256u) {
                float acc[32];
#pragma unroll
                for (int co = 0; co < 32; co++) acc[co] = stem_bf[co];
#pragma unroll
                for (int tap = 0; tap < 9; tap++) {
                    float v = xs[(r + tap/3)*20 + (c + tap%3)];
                    const float* w = &wf0[tap*32];
#pragma unroll
                    for (int co = 0; co < 32; co++) acc[co] = fmaf(v, w[co], acc[co]);
                }
                // k' packing: word m holds channels (m, m+16)
                u32* ow = (u32*)qv;
#pragma unroll
                for (int m = 0; m < 16; m++)
                    ow[m] = pack2bf(fmaxf(acc[m], 0.f), fmaxf(acc[m+16], 0.f));
            }
#pragma unroll
            for (int q = 0; q < 4; q++)
                *(uint4*)&tileq[(q*324 + pp)*8] = qv[q];
        }
    }
    __syncthreads();

    float cn2adj[16];
#pragma unroll
    for (int nt = 0; nt < 16; nt++) cn2adj[nt] = 0.25f*cn2[nt*16+col] + 0.5f;
    float bu1C0 = up1_b[col], bu1C1 = up1_b[col+16];
    float bu2_0 = up2_b[col], bu2_1 = up2_b[col+16];
    float bt0 = tau_b[col],   bt1 = tau_b[col+16];
    u16* hzw = &hzb[wave*512];
    u32* hz32 = (u32*)hzw;
    int wy = wave * 4;
    f4_t kz = {0.f,0.f,0.f,0.f};

    bf8_t rows[4][3];
#pragma unroll
    for (int i = 0; i < 4; i++)
#pragma unroll
        for (int dx = 0; dx < 3; dx++)
            rows[i][dx] = *(const bf8_t*)&tileq[(quad*324 + (wy+i)*18 + col+dx)*8];

#pragma unroll
    for (int rrp = 0; rrp < 2; rrp++) {
        if (rrp) {
#pragma unroll
            for (int dx = 0; dx < 3; dx++) {
                rows[0][dx] = rows[2][dx];
                rows[1][dx] = rows[3][dx];
                rows[2][dx] = *(const bf8_t*)&tileq[(quad*324 + (wy+4)*18 + col+dx)*8];
                rows[3][dx] = *(const bf8_t*)&tileq[(quad*324 + (wy+5)*18 + col+dx)*8];
            }
        }
        f4_t aA0 = kz, aA1 = kz, aB0 = kz, aB1 = kz;
#pragma unroll
        for (int t = 0; t < 9; t++) {
            int dy = t/3, dx = t - dy*3;
            bf8_t wA = *(const bf8_t*)&w1f[((t*2+0)*64 + lane)*8];
            bf8_t wB = *(const bf8_t*)&w1f[((t*2+1)*64 + lane)*8];
            aA0 = MFMA16(rows[dy  ][dx], wA, aA0, 0, 0, 0);
            aA1 = MFMA16(rows[dy  ][dx], wB, aA1, 0, 0, 0);
            aB0 = MFMA16(rows[dy+1][dx], wA, aB0, 0, 0, 0);
            aB1 = MFMA16(rows[dy+1][dx], wB, aB1, 0, 0, 0);
        }
        // h transposes: u32 m-major writes, b128 reads (k' layout)
#pragma unroll
        for (int r = 0; r < 4; r++) {
            int px = quad*4 + r;
            hz32[px*16 + col] = pack2bf(fmaxf(aA0[r] + bu1C0, 0.f),
                                        fmaxf(aA1[r] + bu1C1, 0.f));
        }
        LDS_ORDER();
        bf8_t hA0 = *(const bf8_t*)&hzw[col*32 + quad*8];
        LDS_ORDER();
#pragma unroll
        for (int r = 0; r < 4; r++) {
            int px = quad*4 + r;
            hz32[px*16 + col] = pack2bf(fmaxf(aB0[r] + bu1C0, 0.f),
                                        fmaxf(aB1[r] + bu1C1, 0.f));
        }
        LDS_ORDER();
        bf8_t hA1 = *(const bf8_t*)&hzw[col*32 + quad*8];
        LDS_ORDER();

        bf8_t w20 = *(const bf8_t*)&w2f[(0*64+lane)*8];
        bf8_t w21 = *(const bf8_t*)&w2f[(1*64+lane)*8];
        bf8_t wt0 = *(const bf8_t*)&wtf[(0*64+lane)*8];
        bf8_t wt1 = *(const bf8_t*)&wtf[(1*64+lane)*8];
        bf8_t sA0 = rows[1][1], sA1 = rows[2][1];
        f4_t d00 = MFMA16(hA0, w20, kz, 0, 0, 0);
        f4_t d01 = MFMA16(hA0, w21, kz, 0, 0, 0);
        f4_t d10 = MFMA16(hA1, w20, kz, 0, 0, 0);
        f4_t d11 = MFMA16(hA1, w21, kz, 0, 0, 0);
        f4_t t00 = MFMA16(sA0, wt0, kz, 0, 0, 0);
        f4_t t01 = MFMA16(sA0, wt1, kz, 0, 0, 0);
        f4_t t10 = MFMA16(sA1, wt0, kz, 0, 0, 0);
        f4_t t11 = MFMA16(sA1, wt1, kz, 0, 0, 0);
        f4_t S0l = MFMA16(sA0, id0, kz, 0, 0, 0);
        f4_t S0h = MFMA16(sA0, id1, kz, 0, 0, 0);
        f4_t S1l = MFMA16(sA1, id0, kz, 0, 0, 0);
        f4_t S1h = MFMA16(sA1, id1, kz, 0, 0, 0);

        // blend + z (row 0), z stored as -0.25*z, u32 m-major
#pragma unroll
        for (int r = 0; r < 4; r++) {
            int px = quad*4 + r;
            float dl0 = d00[r] + bu2_0, tv0 = t00[r] + bt0;
            float be0 = 1.0f / (1.0f + __expf(-tv0));
            float dl1 = d01[r] + bu2_1, tv1 = t01[r] + bt1;
            float be1 = 1.0f / (1.0f + __expf(-tv1));
            hz32[px*16 + col] = pack2bf(-0.25f * (dl0 + be0*(S0l[r] - dl0)),
                                        -0.25f * (dl1 + be1*(S0h[r] - dl1)));
        }
        LDS_ORDER();
        bf8_t zA0 = *(const bf8_t*)&hzw[col*32 + quad*8];
        LDS_ORDER();
        // blend + z (row 1)
#pragma unroll
        for (int r = 0; r < 4; r++) {
            int px = quad*4 + r;
            float dl0 = d10[r] + bu2_0, tv0 = t10[r] + bt0;
            float be0 = 1.0f / (1.0f + __expf(-tv0));
            float dl1 = d11[r] + bu2_1, tv1 = t11[r] + bt1;
            float be1 = 1.0f / (1.0f + __expf(-tv1));
            hz32[px*16 + col] = pack2bf(-0.25f * (dl0 + be0*(S1l[r] - dl0)),
                                        -0.25f * (dl1 + be1*(S1h[r] - dl1)));
        }
        LDS_ORDER();
        bf8_t zA1 = *(const bf8_t*)&hzw[col*32 + quad*8];
        LDS_ORDER();

        // VQ: cbp frag table (k', lane-contiguous -> conflict-free b128)
        u32 b0[4], b1[4];
#pragma unroll
        for (int r = 0; r < 4; r++) { b0[r] = 0xFFFFFFFFu; b1[r] = 0xFFFFFFFFu; }
#pragma unroll
        for (int nt = 0; nt < 16; nt++) {
            bf8_t cf = *(const bf8_t*)&cbf[(nt*64 + lane)*8];
            f4_t ci = {cn2adj[nt], cn2adj[nt], cn2adj[nt], cn2adj[nt]};
            f4_t s0 = MFMA16(zA0, cf, ci, 0, 0, 0);
            f4_t s1 = MFMA16(zA1, cf, ci, 0, 0, 0);
            u32 code = (u32)(nt*16) | (u32)col;
#pragma unroll
            for (int r = 0; r < 4; r++) {
                u32 k0 = (__builtin_bit_cast(u32, s0[r]) & 0xFFFFFF00u) | code;
                u32 k1 = (__builtin_bit_cast(u32, s1[r]) & 0xFFFFFF00u) | code;
                b0[r] = k0 < b0[r] ? k0 : b0[r];
                b1[r] = k1 < b1[r] ? k1 : b1[r];
            }
        }
#pragma unroll
        for (int r = 0; r < 4; r++) {
            DPPMIN(b0[r], 0x121); DPPMIN(b0[r], 0x122);
            DPPMIN(b0[r], 0x124); DPPMIN(b0[r], 0x128);
            DPPMIN(b1[r], 0x121); DPPMIN(b1[r], 0x122);
            DPPMIN(b1[r], 0x124); DPPMIN(b1[r], 0x128);
        }
        int yr = y0 + wy + rrp*2;
        if (col < 4) {
            idx_out[(b*256 + yr    )*256 + x0 + quad*4 + col] = (u8)(b0[col] & 255u);
            idx_out[(b*256 + yr + 1)*256 + x0 + quad*4 + col] = (u8)(b1[col] & 255u);
        }
    }
}

// ===================== steps 2..5: R15 body verbatim (proven 0.0, ~80us) ==========
__global__ __launch_bounds__(256) void step1_kernel(
    const u8* __restrict__ idx_in, u8* __restrict__ idx_out,
    const u16* __restrict__ fragsg, const u16* __restrict__ cbr_g,
    const float* __restrict__ cadj_g,
    const float* __restrict__ up1_b, const float* __restrict__ up2_b,
    const float* __restrict__ tau_b)
{
    __shared__ __align__(16) u16 smem[24104];   // 48208 B
    u16* w1f = smem;                       // 9216 (k'-order)
    u16* w2f = smem + 9216;                // 1024
    u16* wtf = smem + 10240;               // 1024
    u16* cbr = smem + 11264;               // 10280 (257 x CBS, k'-order)
    float* cadjf = (float*)(smem + 21544); // 256 f32
    u16* hzb = smem + 22056;               // 2048

    int tid = threadIdx.x;
    int lane = tid & 63, wave = tid >> 6;
    int col = lane & 15, quad = lane >> 4;
    int b = blockIdx.z, x0 = blockIdx.x * 16, y0 = blockIdx.y * 32;
    int wy = wave * 4;

    bf8_t id0 = *(const bf8_t*)&fragsg[IDP + (0*64+lane)*8];
    bf8_t id1 = *(const bf8_t*)&fragsg[IDP + (1*64+lane)*8];

    // tables -> LDS: w1p|w2p|wtp = 22528 B = 1408 uint4, cbr = 1285, cadj = 64
    {
        const uint4* s4 = (const uint4*)(fragsg + W1P);
        uint4* d4 = (uint4*)smem;
        for (int i = tid; i < 1408; i += 256) d4[i] = s4[i];
        const uint4* c4 = (const uint4*)cbr_g;
        uint4* e4 = (uint4*)cbr;
        for (int i = tid; i < 1285; i += 256) e4[i] = c4[i];
        const uint4* a4 = (const uint4*)cadj_g;
        uint4* f4p = (uint4*)cadjf;
        if (tid < 64) f4p[tid] = a4[tid];
    }
    __syncthreads();

    float bu1C0 = up1_b[col], bu1C1 = up1_b[col+16];
    float bu2_0 = up2_b[col], bu2_1 = up2_b[col+16];
    float bt0 = tau_b[col],   bt1 = tau_b[col+16];
    u16* hzw = &hzb[wave*512];
    u32* hz32 = (u32*)hzw;
    f4_t kz = {0.f,0.f,0.f,0.f};

    for (int th = 0; th < 2; th++) {
        int yb = y0 + th*16;

        u32 kp[6];
#pragma unroll
        for (int tr = 0; tr < 6; tr++) {
            u32 pk = 0;
#pragma unroll
            for (int dx = 0; dx < 3; dx++) {
                int gy = yb - 1 + wy + tr, gx = x0 - 1 + col + dx;
                bool ok = ((unsigned)gy < 256u) & ((unsigned)gx < 256u);
                u32 c = ok ? (u32)idx_in[(b << 16) | (gy << 8) | gx] : 256u;
                pk |= c << (9*dx);
            }
            kp[tr] = pk;
        }

        f4_t acc[4][2];
#pragma unroll
        for (int r4 = 0; r4 < 4; r4++) { acc[r4][0] = kz; acc[r4][1] = kz; }
        bf8_t sA[4];
#pragma unroll
        for (int t = 0; t < 9; t++) {
            int dy = t/3, dx = t - dy*3;
            bf8_t wA = *(const bf8_t*)&w1f[((t*2+0)*64 + lane)*8];
            bf8_t wB = *(const bf8_t*)&w1f[((t*2+1)*64 + lane)*8];
#pragma unroll
            for (int r4 = 0; r4 < 4; r4++) {
                int k = (int)((kp[r4+dy] >> (9*dx)) & 511u);
                bf8_t f = *(const bf8_t*)&cbr[k*CBS + quad*8];
                if (t == 4) sA[r4] = f;
                acc[r4][0] = MFMA16(f, wA, acc[r4][0], 0, 0, 0);
                acc[r4][1] = MFMA16(f, wB, acc[r4][1], 0, 0, 0);
            }
        }

        bf8_t w20 = *(const bf8_t*)&w2f[(0*64+lane)*8];
        bf8_t w21 = *(const bf8_t*)&w2f[(1*64+lane)*8];
        bf8_t wt0 = *(const bf8_t*)&wtf[(0*64+lane)*8];
        bf8_t wt1 = *(const bf8_t*)&wtf[(1*64+lane)*8];

        bf8_t zA[4];
#pragma unroll
        for (int r4 = 0; r4 < 4; r4++) {
#pragma unroll
            for (int r = 0; r < 4; r++) {
                int px = quad*4 + r;
                hz32[px*16 + col] = pack2bf(fmaxf(acc[r4][0][r] + bu1C0, 0.f),
                                            fmaxf(acc[r4][1][r] + bu1C1, 0.f));
            }
            LDS_ORDER();
            bf8_t hA = *(const bf8_t*)&hzw[col*32 + quad*8];
            LDS_ORDER();
            f4_t d0 = MFMA16(hA, w20, kz, 0, 0, 0);
            f4_t d1 = MFMA16(hA, w21, kz, 0, 0, 0);
            f4_t t0 = MFMA16(sA[r4], wt0, kz, 0, 0, 0);
            f4_t t1 = MFMA16(sA[r4], wt1, kz, 0, 0, 0);
            f4_t Sl = MFMA16(sA[r4], id0, kz, 0, 0, 0);
            f4_t Sh = MFMA16(sA[r4], id1, kz, 0, 0, 0);
#pragma unroll
            for (int r = 0; r < 4; r++) {
                int px = quad*4 + r;
                float dl0 = d0[r] + bu2_0, tv0 = t0[r] + bt0;
                float be0 = 1.0f / (1.0f + __expf(-tv0));
                float dl1 = d1[r] + bu2_1, tv1 = t1[r] + bt1;
                float be1 = 1.0f / (1.0f + __expf(-tv1));
                hz32[px*16 + col] = pack2bf(-0.25f * (dl0 + be0*(Sl[r] - dl0)),
                                            -0.25f * (dl1 + be1*(Sh[r] - dl1)));
            }
            LDS_ORDER();
            zA[r4] = *(const bf8_t*)&hzw[col*32 + quad*8];
            LDS_ORDER();
        }

        u32 bk[4][4];
#pragma unroll
        for (int r4 = 0; r4 < 4; r4++)
#pragma unroll
            for (int r = 0; r < 4; r++) bk[r4][r] = 0xFFFFFFFFu;
#pragma unroll
        for (int nt = 0; nt < 16; nt++) {
            bf8_t cf = *(const bf8_t*)&cbr[(nt*16 + col)*CBS + quad*8];
            float ca = cadjf[nt*16 + col];
            f4_t ci = {ca, ca, ca, ca};
            u32 code = (u32)(nt*16) | (u32)col;
#pragma unroll
            for (int r4 = 0; r4 < 4; r4++) {
                f4_t sc = MFMA16(zA[r4], cf, ci, 0, 0, 0);
#pragma unroll
                for (int r = 0; r < 4; r++) {
                    u32 k0 = (__builtin_bit_cast(u32, sc[r]) & 0xFFFFFF00u) | code;
                    bk[r4][r] = k0 < bk[r4][r] ? k0 : bk[r4][r];
                }
            }
        }
#pragma unroll
        for (int r4 = 0; r4 < 4; r4++) {
#pragma unroll
            for (int r = 0; r < 4; r++) {
                DPPMIN(bk[r4][r], 0x121); DPPMIN(bk[r4][r], 0x122);
                DPPMIN(bk[r4][r], 0x124); DPPMIN(bk[r4][r], 0x128);
            }
            int yr = yb + wy + r4;
            if (col < 4)
                idx_out[(b*256 + yr)*256 + x0 + quad*4 + col] = (u8)(bk[r4][col] & 255u);
        }
    }
}

// ============================ dec ============================
__global__ __launch_bounds__(256) void dec_kernel(const u8* __restrict__ idx,
        const float* __restrict__ decdot, const int* __restrict__ flagp,
        void* __restrict__ out)
{
    int p = blockIdx.x * 256 + threadIdx.x;
    float s = decdot[idx[p]];
    float r = 1.0f / (1.0f + __expf(-s));
    if (*flagp) ((float*)out)[p] = r;
    else        ((u16*)out)[p]   = f2bf(r);
}

extern "C" void kernel_launch(void* const* d_in, const int* in_sizes, int n_in,
                              void* d_out, int out_size, void* d_ws, size_t ws_size,
                              hipStream_t stream)
{
    const void* x      = d_in[0];
    const void* stem_w = d_in[1];
    const void* stem_b = d_in[2];
    const void* up1_w  = d_in[3];
    const void* up1_b  = d_in[4];
    const void* up2_w  = d_in[5];
    const void* up2_b  = d_in[6];
    const void* tau_w  = d_in[7];
    const void* tau_b  = d_in[8];
    const void* cb     = d_in[9];
    const void* dec_w  = d_in[10];
    const void* dec_b  = d_in[11];
    // d_in[12] = n_steps (fixed at 5 by the problem definition)

    char* ws = (char*)d_ws;
    size_t off = 0;
    auto carve = [&](size_t bytes) -> void* {
        void* p = ws + off;
        off += (bytes + 255) & ~(size_t)255;
        return p;
    };
    u8*    idxA    = (u8*)   carve(NPIX);
    u8*    idxB    = (u8*)   carve(NPIX);
    u16*   frags   = (u16*)  carve(FRAGS_TOT * 2);  // k-order + k'-order tables
    u16*   cb_bf   = (u16*)  carve(257*CBS * 2);    // k'-order padded rows
    float* cn2     = (float*)carve(256 * 4);
    float* cadj    = (float*)carve(256 * 4);
    float* decdot  = (float*)carve(256 * 4);
    float* wf0     = (float*)carve(288 * 4);
    float* up1_bf  = (float*)carve(32 * 4);
    float* up2_bf  = (float*)carve(32 * 4);
    float* tau_bf  = (float*)carve(32 * 4);
    float* stem_bf = (float*)carve(32 * 4);
    int*   flag    = (int*)  carve(4);

    prep_kernel<<<205, 256, 0, stream>>>(x, stem_w, stem_b, up1_w, up1_b,
        up2_w, up2_b, tau_w, tau_b, cb, dec_w, dec_b,
        frags, cb_bf, cn2, cadj, decdot, wf0,
        up1_bf, up2_bf, tau_bf, stem_bf, flag);

    dim3 g0(WW/16, HH/16, BATCH);
    step0_kernel<<<g0, 256, 0, stream>>>(x, flag, idxA,
        frags, cn2, up1_bf, up2_bf, tau_bf, wf0, stem_bf);
    dim3 g1(WW/16, HH/32, BATCH);
    u8* cur = idxA; u8* nxt = idxB;
    for (int t = 1; t < NSTEPS; t++) {
        step1_kernel<<<g1, 256, 0, stream>>>(cur, nxt, frags, cb_bf, cadj,
                                             up1_bf, up2_bf, tau_bf);
        u8* tmp = cur; cur = nxt; nxt = tmp;
    }
    dec_kernel<<<NPIX/256, 256, 0, stream>>>(cur, decdot, flag, d_out);
}